// Round 8
// baseline (412.581 us; speedup 1.0000x reference)
//
#include <hip/hip_runtime.h>

constexpr int B = 8, S = 2048, D = 256;
constexpr int TQ = 32;              // query rows per block (main kernel)
constexpr float SCALE = 0.0625f;    // 1/sqrt(256)
constexpr int PSTRIDE = 2056;       // 2048 + 8 bf16 pad -> 2-way bank aliasing (free)

typedef __attribute__((ext_vector_type(8))) short bf16x8;  // 8 bf16 in 4 VGPRs
typedef __attribute__((ext_vector_type(4))) float f32x4;

__device__ __forceinline__ short f2bf(float f) {
    union { float f; unsigned u; } c; c.f = f;
    unsigned u = c.u + 0x7fffu + ((c.u >> 16) & 1u);   // RNE
    return (short)(u >> 16);
}

// ---- minimal pre-pass: convK | transposeV only ----
// grid: [0,4096) convK, [4096,5120) transposeV
__global__ __launch_bounds__(256) void prepass(
    const float* __restrict__ k, const float* __restrict__ v,
    short* __restrict__ kb, short* __restrict__ vtb)
{
    __shared__ float tile[64][65];
    const int blk = blockIdx.x;
    const int tid = threadIdx.x;

    if (blk < 4096) {
        // ---- conv k: fp32 -> bf16, float4 granularity ----
        int i = blk * 256 + tid;
        float4 x = ((const float4*)k)[i];
        short4 o; o.x = f2bf(x.x); o.y = f2bf(x.y); o.z = f2bf(x.z); o.w = f2bf(x.w);
        ((short4*)kb)[i] = o;
    } else {
        // ---- transpose V: [B][S][D] fp32 -> [B][D][S] bf16 ----
        int blk2 = blk - 4096;
        int b = blk2 >> 7, rem = blk2 & 127;
        int d0 = (rem & 3) * 64, k0 = (rem >> 2) * 64;
        int tr = tid >> 4, tc = tid & 15;
        const float* vb = v + (size_t)b * S * D;
        #pragma unroll
        for (int r = 0; r < 4; ++r) {
            int key = r * 16 + tr;
            float4 x = *(const float4*)(vb + (size_t)(k0 + key) * D + d0 + tc * 4);
            tile[key][tc * 4 + 0] = x.x; tile[key][tc * 4 + 1] = x.y;
            tile[key][tc * 4 + 2] = x.z; tile[key][tc * 4 + 3] = x.w;
        }
        __syncthreads();
        short* vtbb = vtb + (size_t)b * D * S;
        #pragma unroll
        for (int r = 0; r < 4; ++r) {
            int d = r * 16 + tr;
            short4 o;
            o.x = f2bf(tile[tc * 4 + 0][d]); o.y = f2bf(tile[tc * 4 + 1][d]);
            o.z = f2bf(tile[tc * 4 + 2][d]); o.w = f2bf(tile[tc * 4 + 3][d]);
            *(short4*)(vtbb + (size_t)(d0 + d) * S + k0 + tc * 4) = o;
        }
    }
}

// ---- main fused kernel: 512 threads (8 waves), 1 block = 32 q-rows x 1 batch ----
// SWAPPED QK^T (R7): acc[mt][nt][r] = S[key = wave*256+nt*16+quad*4+r][q = i0+mt*16+l16]
// -> mask read = int4/lane, attn write = float4/lane.
// R8 changes (scheduling only, traffic identical):
//  1. mask+exp+rowsum folded into phase A's nt loop: the 134 MB mask stream
//     drains under MFMA/K-load work instead of serializing up front (~50 us).
//  2. raw s_barrier (lgkmcnt-only wait) before phase C: the 134 MB attn store
//     stream stays in flight and retires under phase C instead of being
//     vmcnt(0)-drained at __syncthreads (~35-45 us serial).
// LDS: p_lds 128.5 KB + red 1 KB -> 1 block/CU. XCD-batch affinity kept (R5).
__global__ __launch_bounds__(512, 2) void attn_mfma(
    const float* __restrict__ qf, const short* __restrict__ kb,
    const short* __restrict__ vtb, const int* __restrict__ maskg,
    float* __restrict__ outg, float* __restrict__ attng)
{
    const int b = blockIdx.x & 7;              // XCD-affine batch
    const int i0 = (blockIdx.x >> 3) * TQ;     // q-tile within batch
    const int tid = threadIdx.x;
    const int wave = tid >> 6, lane = tid & 63;
    const int quad = lane >> 4, l16 = lane & 15;

    __shared__ short p_lds[TQ][PSTRIDE];
    __shared__ float red[8][TQ];

    // ---------- Q fp32 -> bf16 in-register (no cross-block reuse -> no prepass) ----------
    bf16x8 aq[2][8];
    const float* qbase = qf + ((size_t)b * S + i0) * D;
    #pragma unroll
    for (int mt = 0; mt < 2; ++mt)
        #pragma unroll
        for (int ks = 0; ks < 8; ++ks) {
            const float* p = qbase + (size_t)(mt * 16 + l16) * D + ks * 32 + quad * 8;
            float4 x0 = *(const float4*)p;
            float4 x1 = *(const float4*)(p + 4);
            bf16x8 a;
            a[0] = f2bf(x0.x); a[1] = f2bf(x0.y); a[2] = f2bf(x0.z); a[3] = f2bf(x0.w);
            a[4] = f2bf(x1.x); a[5] = f2bf(x1.y); a[6] = f2bf(x1.z); a[7] = f2bf(x1.w);
            aq[mt][ks] = a;
        }

    f32x4 acc[2][16];
    #pragma unroll
    for (int mt = 0; mt < 2; ++mt)
        #pragma unroll
        for (int nt = 0; nt < 16; ++nt)
            acc[mt][nt] = f32x4{0.f, 0.f, 0.f, 0.f};

    // ---------- phase A: S^T = K Q^T with mask+exp+rowsum fused per nt ----------
    float rsum[2] = {0.f, 0.f};
    const short* kbase = kb + (size_t)b * S * D;
    const int* mbase0 = maskg + ((size_t)b * S + i0 + l16) * S + wave * 256 + quad * 4;
    const int* mbase1 = mbase0 + (size_t)16 * S;

    #pragma unroll
    for (int nt = 0; nt < 16; ++nt) {
        const int n0 = wave * 256 + nt * 16;
        // mask loads issued alongside K loads; MFMAs below cover their latency
        int4 m0 = *(const int4*)(mbase0 + nt * 16);
        int4 m1 = *(const int4*)(mbase1 + nt * 16);
        bf16x8 bk[8];
        #pragma unroll
        for (int ks = 0; ks < 8; ++ks)
            bk[ks] = *(const bf16x8*)(kbase + (size_t)(n0 + l16) * D + ks * 32 + quad * 8);
        #pragma unroll
        for (int ks = 0; ks < 8; ++ks) {
            // swapped: first operand K -> C row = key, second Q -> C col = q
            acc[0][nt] = __builtin_amdgcn_mfma_f32_16x16x32_bf16(bk[ks], aq[0][ks], acc[0][nt], 0, 0, 0);
            acc[1][nt] = __builtin_amdgcn_mfma_f32_16x16x32_bf16(bk[ks], aq[1][ks], acc[1][nt], 0, 0, 0);
        }
        // consume this nt's scores: mask (0 == reference's exp(-1e9) underflow), exp, row-sum
        const int mm0[4] = {m0.x, m0.y, m0.z, m0.w};
        const int mm1[4] = {m1.x, m1.y, m1.z, m1.w};
        #pragma unroll
        for (int r = 0; r < 4; ++r) {
            float e0 = mm0[r] ? __expf(acc[0][nt][r] * SCALE) : 0.0f;
            acc[0][nt][r] = e0; rsum[0] += e0;
            float e1 = mm1[r] ? __expf(acc[1][nt][r] * SCALE) : 0.0f;
            acc[1][nt][r] = e1; rsum[1] += e1;
        }
    }

    // ---------- reduce row-sums across the 4 quads + 8 waves ----------
    #pragma unroll
    for (int mt = 0; mt < 2; ++mt) {
        float v = rsum[mt];
        v += __shfl_xor(v, 16); v += __shfl_xor(v, 32);
        if (quad == 0) red[wave][mt * 16 + l16] = v;
    }
    __syncthreads();   // cheap: all outstanding VMEM already consumed

    float inv[2];
    #pragma unroll
    for (int mt = 0; mt < 2; ++mt) {
        float tot = 0.f;
        #pragma unroll
        for (int w = 0; w < 8; ++w) tot += red[w][mt * 16 + l16];
        inv[mt] = 1.0f / tot;
    }

    // normalize; attn write = float4/lane, batched (R3: batching preserves L2
    // write-combining); p_lds stash = short4/lane.
    #pragma unroll
    for (int mt = 0; mt < 2; ++mt) {
        float* arow = attng + ((size_t)b * S + i0 + mt * 16 + l16) * S + wave * 256 + quad * 4;
        #pragma unroll
        for (int nt = 0; nt < 16; ++nt) {
            float4 p4; short4 pb;
            float p0 = acc[mt][nt][0] * inv[mt];
            float p1 = acc[mt][nt][1] * inv[mt];
            float p2 = acc[mt][nt][2] * inv[mt];
            float p3 = acc[mt][nt][3] * inv[mt];
            p4.x = p0; p4.y = p1; p4.z = p2; p4.w = p3;
            pb.x = f2bf(p0); pb.y = f2bf(p1); pb.z = f2bf(p2); pb.w = f2bf(p3);
            *(float4*)(arow + nt * 16) = p4;
            *(short4*)&p_lds[mt * 16 + l16][wave * 256 + nt * 16 + quad * 4] = pb;
        }
    }

    // raw barrier: wait only for LDS writes (p_lds), NOT the attn global stores.
    // __syncthreads would emit s_waitcnt vmcnt(0) and serially drain 256 KB/block;
    // with the raw barrier the stores retire under phase C's loads/MFMAs.
    asm volatile("s_waitcnt lgkmcnt(0)" ::: "memory");
    __builtin_amdgcn_s_barrier();
    asm volatile("" ::: "memory");   // keep phase C's ds_reads below the barrier

    // ---------- phase C: out = P V (wave w owns dims [w*32, w*32+32)) ----------
    f32x4 oacc[2][2];
    #pragma unroll
    for (int mt = 0; mt < 2; ++mt)
        #pragma unroll
        for (int nc = 0; nc < 2; ++nc) oacc[mt][nc] = f32x4{0.f, 0.f, 0.f, 0.f};

    const short* vbase = vtb + (size_t)b * D * S;
    const int nb = wave * 32;
    for (int ks = 0; ks < 64; ++ks) {
        bf16x8 ap[2], bv[2];
        #pragma unroll
        for (int mt = 0; mt < 2; ++mt)
            ap[mt] = *(const bf16x8*)&p_lds[mt * 16 + l16][ks * 32 + quad * 8];
        #pragma unroll
        for (int nc = 0; nc < 2; ++nc)
            bv[nc] = *(const bf16x8*)(vbase + (size_t)(nb + nc * 16 + l16) * S + ks * 32 + quad * 8);
        #pragma unroll
        for (int mt = 0; mt < 2; ++mt)
            #pragma unroll
            for (int nc = 0; nc < 2; ++nc)
                oacc[mt][nc] = __builtin_amdgcn_mfma_f32_16x16x32_bf16(ap[mt], bv[nc], oacc[mt][nc], 0, 0, 0);
    }

    #pragma unroll
    for (int mt = 0; mt < 2; ++mt)
        #pragma unroll
        for (int nc = 0; nc < 2; ++nc)
            #pragma unroll
            for (int r = 0; r < 4; ++r) {
                int row = i0 + mt * 16 + quad * 4 + r;
                int col = nb + nc * 16 + l16;
                outg[((size_t)b * S + row) * D + col] = oacc[mt][nc][r];
            }
}

extern "C" void kernel_launch(void* const* d_in, const int* in_sizes, int n_in,
                              void* d_out, int out_size, void* d_ws, size_t ws_size,
                              hipStream_t stream) {
    const float* q    = (const float*)d_in[0];
    const float* k    = (const float*)d_in[1];
    const float* v    = (const float*)d_in[2];
    const int*   mask = (const int*)d_in[3];
    float* out  = (float*)d_out;
    float* attn = out + (size_t)B * S * D;     // tuple order: (out, attn)

    const size_t N = (size_t)B * S * D;        // 4,194,304 elements
    short* kb  = (short*)d_ws;                 // 8 MB
    short* vtb = kb + N;                       // 8 MB (transposed V)

    prepass<<<dim3(5120), 256, 0, stream>>>(k, v, kb, vtb);
    attn_mfma<<<dim3((S / TQ) * B), 512, 0, stream>>>(q, kb, vtb, mask, out, attn);
}